// Round 1
// baseline (2767.077 us; speedup 1.0000x reference)
//
#include <hip/hip_runtime.h>
#include <cstdint>
#include <cstddef>

// Problem constants
#define NB 4096
#define NL 50
#define NT 64
#define NF 3
#define NH 20
#define NO 16
#define NN (NB*NL)   // 204800 sequences

// ---------------- fast transcendentals (v_exp_f32 + v_rcp_f32) ----------------
__device__ __forceinline__ float fsig(float z) {
    // 1/(1+exp(-z))
    return __builtin_amdgcn_rcpf(1.0f + __expf(-z));
}
__device__ __forceinline__ float ftanh(float z) {
    // 1 - 2/(1+exp(2z)); stable at +/-inf
    return 1.0f - 2.0f * __builtin_amdgcn_rcpf(1.0f + __expf(2.0f * z));
}

// ---------------- counting sort by length (64 buckets) ----------------
__global__ __launch_bounds__(256) void hist_kernel(const int* __restrict__ lengths,
                                                   int* __restrict__ hist) {
    __shared__ int lh[64];
    int tid = threadIdx.x;
    if (tid < 64) lh[tid] = 0;
    __syncthreads();
    int n = blockIdx.x * 256 + tid;
    if (n < NN) {
        int len = lengths[n];
        len = len < 0 ? 0 : (len > 63 ? 63 : len);
        atomicAdd(&lh[len], 1);
    }
    __syncthreads();
    if (tid < 64 && lh[tid] != 0) atomicAdd(&hist[tid], lh[tid]);
}

__global__ void scan_kernel(const int* __restrict__ hist, int* __restrict__ cursor) {
    if (threadIdx.x == 0) {
        int s = 0;
        for (int k = 0; k < 64; ++k) { cursor[k] = s; s += hist[k]; }
    }
}

__global__ __launch_bounds__(256) void scatter_kernel(const int* __restrict__ lengths,
                                                      int* __restrict__ cursor,
                                                      int* __restrict__ order) {
    __shared__ int lcnt[64];
    __shared__ int lbase[64];
    int tid = threadIdx.x;
    if (tid < 64) lcnt[tid] = 0;
    __syncthreads();
    int n = blockIdx.x * 256 + tid;
    int len = 0, myrank = 0;
    if (n < NN) {
        len = lengths[n];
        len = len < 0 ? 0 : (len > 63 ? 63 : len);
        myrank = atomicAdd(&lcnt[len], 1);
    }
    __syncthreads();
    if (tid < 64 && lcnt[tid] != 0) lbase[tid] = atomicAdd(&cursor[tid], lcnt[tid]);
    __syncthreads();
    if (n < NN) order[lbase[len] + myrank] = n;
}

// ---------------- LSTM + summary linear (one sequence per thread) ----------------
__global__ __launch_bounds__(256, 4) void lstm_kernel(
    const float* __restrict__ x,        // [NN][NT][NF]
    const int*   __restrict__ lengths,  // [NN]
    const int*   __restrict__ order,    // [NN] sorted-by-length indices
    const float* __restrict__ w_ih,     // [80][3]
    const float* __restrict__ w_hh,     // [80][20]
    const float* __restrict__ b_ih,     // [80]
    const float* __restrict__ b_hh,     // [80]
    const float* __restrict__ w_lin,    // [16][20]
    const float* __restrict__ b_lin,    // [16]
    float* __restrict__ feat)           // [NN][16]
{
    int i = blockIdx.x * 256 + threadIdx.x;
    if (i >= NN) return;
    int n = order[i];
    int len = lengths[n];
    len = len < 0 ? 0 : (len > NT ? NT : len);

    float h[NH], c[NH];
#pragma unroll
    for (int u = 0; u < NH; ++u) { h[u] = 0.0f; c[u] = 0.0f; }

    const float* xp = x + (size_t)n * (NT * NF);
    for (int t = 0; t < len; ++t) {
        float x0 = xp[t * 3 + 0];
        float x1 = xp[t * 3 + 1];
        float x2 = xp[t * 3 + 2];
        float hn[NH];
#pragma unroll
        for (int u = 0; u < NH; ++u) {
            float z[4];
#pragma unroll
            for (int g = 0; g < 4; ++g) {
                int r = g * NH + u;   // torch gate order i,f,g,o
                float a = b_ih[r] + b_hh[r];
                a += w_ih[r * 3 + 0] * x0;
                a += w_ih[r * 3 + 1] * x1;
                a += w_ih[r * 3 + 2] * x2;
#pragma unroll
                for (int k = 0; k < NH; ++k) a += w_hh[r * NH + k] * h[k];
                z[g] = a;
            }
            float ig = fsig(z[0]);
            float fg = fsig(z[1]);
            float gg = ftanh(z[2]);
            float og = fsig(z[3]);
            float cn = fg * c[u] + ig * gg;
            c[u]  = cn;
            hn[u] = og * ftanh(cn);
        }
#pragma unroll
        for (int u = 0; u < NH; ++u) h[u] = hn[u];
    }

    float* fp = feat + (size_t)n * NO;
    if (len > 0) {
#pragma unroll
        for (int o = 0; o < NO; ++o) {
            float a = b_lin[o];
#pragma unroll
            for (int k = 0; k < NH; ++k) a += w_lin[o * NH + k] * h[k];
            fp[o] = fsig(a);
        }
    } else {
#pragma unroll
        for (int o = 0; o < NO; ++o) fp[o] = 0.0f;
    }
}

// ---------------- conv stack + fc head (one wave per batch row) ----------------
__global__ __launch_bounds__(64) void head_kernel(
    const float* __restrict__ feat,  // [NB][NL][16]
    const float* __restrict__ c1w, const float* __restrict__ c1b,   // [32][16][5], [32]
    const float* __restrict__ c2w, const float* __restrict__ c2b,   // [32][32][4], [32]
    const float* __restrict__ c3w, const float* __restrict__ c3b,   // [32][32][4], [32]
    const float* __restrict__ f1w, const float* __restrict__ f1b,   // [16][608], [16]
    const float* __restrict__ f2w, const float* __restrict__ f2b,   // [4][16], [4]
    float* __restrict__ out)         // [NB][4]
{
    const int b   = blockIdx.x;
    const int tid = threadIdx.x;

    __shared__ float sf[16 * 50];   // [ch][pos]
    __shared__ float y1[32 * 46];
    __shared__ float y2[32 * 22];
    __shared__ float y3[32 * 19];
    __shared__ float r1[16];

    const float* fb = feat + (size_t)b * (NL * NO);
    for (int i = tid; i < NL * NO; i += 64) {
        int l = i >> 4, o = i & 15;
        sf[o * 50 + l] = fb[i];
    }
    __syncthreads();

    // conv1: 16ch k5 s1 -> 32ch x 46, relu
    if (tid < 46) {
        float acc[32];
#pragma unroll
        for (int oc = 0; oc < 32; ++oc) acc[oc] = c1b[oc];
#pragma unroll
        for (int ic = 0; ic < 16; ++ic) {
#pragma unroll
            for (int tap = 0; tap < 5; ++tap) {
                float fv = sf[ic * 50 + tid + tap];
#pragma unroll
                for (int oc = 0; oc < 32; ++oc)
                    acc[oc] += c1w[(oc * 16 + ic) * 5 + tap] * fv;
            }
        }
#pragma unroll
        for (int oc = 0; oc < 32; ++oc) y1[oc * 46 + tid] = fmaxf(acc[oc], 0.0f);
    }
    __syncthreads();

    // conv2: 32ch k4 s2 -> 32ch x 22, relu
    if (tid < 22) {
        float acc[32];
#pragma unroll
        for (int oc = 0; oc < 32; ++oc) acc[oc] = c2b[oc];
#pragma unroll
        for (int ic = 0; ic < 32; ++ic) {
#pragma unroll
            for (int tap = 0; tap < 4; ++tap) {
                float fv = y1[ic * 46 + 2 * tid + tap];
#pragma unroll
                for (int oc = 0; oc < 32; ++oc)
                    acc[oc] += c2w[(oc * 32 + ic) * 4 + tap] * fv;
            }
        }
#pragma unroll
        for (int oc = 0; oc < 32; ++oc) y2[oc * 22 + tid] = fmaxf(acc[oc], 0.0f);
    }
    __syncthreads();

    // conv3: 32ch k4 s1 -> 32ch x 19, relu
    if (tid < 19) {
        float acc[32];
#pragma unroll
        for (int oc = 0; oc < 32; ++oc) acc[oc] = c3b[oc];
#pragma unroll
        for (int ic = 0; ic < 32; ++ic) {
#pragma unroll
            for (int tap = 0; tap < 4; ++tap) {
                float fv = y2[ic * 22 + tid + tap];
#pragma unroll
                for (int oc = 0; oc < 32; ++oc)
                    acc[oc] += c3w[(oc * 32 + ic) * 4 + tap] * fv;
            }
        }
#pragma unroll
        for (int oc = 0; oc < 32; ++oc) y3[oc * 19 + tid] = fmaxf(acc[oc], 0.0f);
    }
    __syncthreads();

    // fc1: 608 -> 16, relu. lane = (u, quarter); 152 k's per lane; shfl reduce.
    {
        int u = tid & 15;
        int q = tid >> 4;          // 0..3
        float acc = 0.0f;
        int k0 = q * 152;
#pragma unroll 8
        for (int k = k0; k < k0 + 152; ++k) acc += f1w[u * 608 + k] * y3[k];
        acc += __shfl_xor(acc, 16);
        acc += __shfl_xor(acc, 32);
        if (tid < 16) r1[tid] = fmaxf(acc + f1b[tid], 0.0f);
    }
    __syncthreads();

    // fc2: 16 -> 4
    if (tid < 4) {
        float s = f2b[tid];
#pragma unroll
        for (int k = 0; k < 16; ++k) s += f2w[tid * 16 + k] * r1[k];
        out[(size_t)b * 4 + tid] = s;
    }
}

extern "C" void kernel_launch(void* const* d_in, const int* in_sizes, int n_in,
                              void* d_out, int out_size, void* d_ws, size_t ws_size,
                              hipStream_t stream)
{
    const float* x     = (const float*)d_in[0];
    const int*  lengths= (const int*)  d_in[1];
    const float* w_ih  = (const float*)d_in[2];
    const float* w_hh  = (const float*)d_in[3];
    const float* b_ih  = (const float*)d_in[4];
    const float* b_hh  = (const float*)d_in[5];
    const float* w_lin = (const float*)d_in[6];
    const float* b_lin = (const float*)d_in[7];
    const float* c1w   = (const float*)d_in[8];
    const float* c1b   = (const float*)d_in[9];
    const float* c2w   = (const float*)d_in[10];
    const float* c2b   = (const float*)d_in[11];
    const float* c3w   = (const float*)d_in[12];
    const float* c3b   = (const float*)d_in[13];
    const float* f1w   = (const float*)d_in[14];
    const float* f1b   = (const float*)d_in[15];
    const float* f2w   = (const float*)d_in[16];
    const float* f2b   = (const float*)d_in[17];
    float* out = (float*)d_out;

    // workspace layout
    char* ws    = (char*)d_ws;
    int* hist   = (int*)ws;               // 64
    int* cursor = hist + 64;              // 64
    int* order  = cursor + 64;            // NN
    float* feat = (float*)(order + NN);   // NN*16 floats

    hipMemsetAsync(hist, 0, 64 * sizeof(int), stream);
    hist_kernel   <<<NN / 256, 256, 0, stream>>>(lengths, hist);
    scan_kernel   <<<1, 64, 0, stream>>>(hist, cursor);
    scatter_kernel<<<NN / 256, 256, 0, stream>>>(lengths, cursor, order);
    lstm_kernel   <<<NN / 256, 256, 0, stream>>>(x, lengths, order,
                                                 w_ih, w_hh, b_ih, b_hh,
                                                 w_lin, b_lin, feat);
    head_kernel   <<<NB, 64, 0, stream>>>(feat, c1w, c1b, c2w, c2b, c3w, c3b,
                                          f1w, f1b, f2w, f2b, out);
}